// Round 2
// baseline (470.280 us; speedup 1.0000x reference)
//
#include <hip/hip_runtime.h>

#define H 128
#define W 128
#define C 64
#define NB 8
#define KK 9

typedef __attribute__((ext_vector_type(4))) float f32x4;
typedef __attribute__((ext_vector_type(8))) short short8;

// ws layout (bytes)
//  xt   : bf16 [N][H][W][C]            @ 0         (16777216 B)
//  cd   : float2 [N][9][H][W]          @ 16777216  (9437184 B)
//  wt   : bf16 [9][co][c]              @ 26214400  (73728 B)
//  sums : f32 [128]                    @ 26288128  (512 B)
static constexpr size_t XT_B   = 0;
static constexpr size_t CD_B   = 16777216;
static constexpr size_t WT_B   = 26214400;
static constexpr size_t SUM_B  = 26288128;

__device__ __forceinline__ ushort f2bf(float f) {
  uint u = __float_as_uint(f);
  return (ushort)((u + 0x7fffu + ((u >> 16) & 1u)) >> 16);
}
__device__ __forceinline__ float bf2f(ushort u) {
  return __uint_as_float(((uint)u) << 16);
}

// ---------------- prep: x NCHW->NHWC bf16, w -> wT[k][co][c] bf16, zero sums
__global__ __launch_bounds__(256) void prep_kernel(const float* __restrict__ x,
                                                   const float* __restrict__ w,
                                                   ushort* __restrict__ xt,
                                                   ushort* __restrict__ wt,
                                                   float* __restrict__ sums) {
  int b = blockIdx.x, t = threadIdx.x;
  if (b < 1024) {
    __shared__ float lds[64 * 129];
    int n = b >> 7, h = b & 127;
    const float* xp = x + ((size_t)n * C) * H * W + (size_t)h * W;
    for (int i = t; i < 8192; i += 256) {
      int c = i >> 7, ww = i & 127;
      lds[c * 129 + ww] = xp[(size_t)c * H * W + ww];
    }
    __syncthreads();
    ushort* xo = xt + (((size_t)n * H + h) * W) * C;
    for (int i = t; i < 8192; i += 256) {
      int ww = i >> 6, c = i & 63;
      xo[(size_t)ww * C + c] = f2bf(lds[c * 129 + ww]);
    }
  } else if (b < 1040) {
    int base = (b - 1024) * 2304;
    for (int i = t; i < 2304; i += 256) {
      int idx = base + i;               // idx = co*576 + c*9 + kk
      int co = idx / 576;
      int rem = idx % 576;
      int c = rem / 9, kk = rem % 9;
      wt[(size_t)kk * 4096 + co * 64 + c] = f2bf(w[idx]);
    }
  } else {
    if (t < 128) sums[t] = 0.0f;
  }
}

// ---------------- offset conv (3x3, pad 1) -> sample coords (ys,xs) per (n,k,h,w)
__global__ __launch_bounds__(256) void offs_kernel(const float* __restrict__ x,
                                                   const float* __restrict__ w_off,
                                                   const float* __restrict__ b_off,
                                                   float2* __restrict__ cd) {
  int b = blockIdx.x;
  int n = b >> 6;
  int tile = b & 63;
  int ty0 = (tile >> 3) << 4;
  int tx0 = (tile & 7) << 4;
  int t = threadIdx.x;
  int ty = t >> 4, tx = t & 15;
  __shared__ float lx[16 * 18 * 18];
  float acc[18];
#pragma unroll
  for (int o = 0; o < 18; ++o) acc[o] = 0.f;

  for (int ch = 0; ch < 4; ++ch) {
    __syncthreads();
    for (int i = t; i < 16 * 324; i += 256) {
      int c16 = i / 324, r = i % 324;
      int ry = r / 18, rx = r % 18;
      int gy = ty0 + ry - 1, gx = tx0 + rx - 1;
      float v = 0.f;
      if (gy >= 0 && gy < H && gx >= 0 && gx < W)
        v = x[(((size_t)n * C + ch * 16 + c16) * H + gy) * W + gx];
      lx[i] = v;
    }
    __syncthreads();
    for (int c16 = 0; c16 < 16; ++c16) {
      int c = ch * 16 + c16;
      float xr[9];
#pragma unroll
      for (int dy = 0; dy < 3; ++dy)
#pragma unroll
        for (int dx = 0; dx < 3; ++dx)
          xr[dy * 3 + dx] = lx[c16 * 324 + (ty + dy) * 18 + (tx + dx)];
      const float* wp = w_off + (size_t)c * 9;  // w_off[(o*64+c)*9 + t9]
#pragma unroll
      for (int o = 0; o < 18; ++o) {
#pragma unroll
        for (int t9 = 0; t9 < 9; ++t9)
          acc[o] += xr[t9] * wp[(size_t)o * 576 + t9];
      }
    }
  }
  int h = ty0 + ty, ww = tx0 + tx;
#pragma unroll
  for (int k = 0; k < 9; ++k) {
    float ys = (float)(k / 3 + h - 1) + acc[2 * k] + b_off[2 * k];
    float xs = (float)(k % 3 + ww - 1) + acc[2 * k + 1] + b_off[2 * k + 1];
    cd[(((size_t)n * 9 + k) * H + h) * W + ww] = make_float2(ys, xs);
  }
}

// ---------------- deformable conv via bf16 MFMA: gather + 64x64 GEMM per tap
__global__ __launch_bounds__(256) void conv_kernel(const ushort* __restrict__ xt,
                                                   const float2* __restrict__ cd,
                                                   const ushort* __restrict__ wt,
                                                   const float* __restrict__ bias,
                                                   float* __restrict__ out,
                                                   float* __restrict__ sums) {
  int b = blockIdx.x;
  int n = b >> 8;
  int tile = b & 255;
  int ty0 = (tile >> 4) << 3;
  int tx0 = (tile & 15) << 3;
  int t = threadIdx.x;
  int wv = t >> 6, ln = t & 63;
  int lr = ln & 15, lg = ln >> 4;
  int wco = wv * 16;

  __shared__ float2 cds[576];
  __shared__ ushort w_lds[4096];   // [co][c] bf16, XOR-swizzled
  __shared__ ushort val_lds[4096]; // [pos][c] bf16, XOR-swizzled

  for (int i = t; i < 576; i += 256) {
    int k = i >> 6, pos = i & 63;
    int h = ty0 + (pos >> 3), ww = tx0 + (pos & 7);
    cds[i] = cd[(((size_t)n * 9 + k) * H + h) * W + ww];
  }

  f32x4 acc[4];
#pragma unroll
  for (int tt = 0; tt < 4; ++tt) acc[tt] = (f32x4)(0.f);

  const ushort* xtn = xt + (size_t)n * H * W * C;

  for (int k = 0; k < 9; ++k) {
    __syncthreads();  // also covers cds staging on k==0
    // stage w tap: w_lds[co][c] (swizzled), 16 bf16 per thread
    {
      const ushort* wk = wt + (size_t)k * 4096;
      int i0 = t * 16;
      int co = i0 >> 6;
      int c0 = i0 & 63;
      short8 w0 = *(const short8*)&wk[i0];
      short8 w1 = *(const short8*)&wk[i0 + 8];
      int sw = (co & 7) << 3;
      *(short8*)&w_lds[co * 64 + (c0 ^ sw)] = w0;
      *(short8*)&w_lds[co * 64 + ((c0 + 8) ^ sw)] = w1;
    }
    // gather val[pos][c=ln] (swizzled); wave wv covers pos = wv*16 .. +15
    for (int pp = 0; pp < 16; ++pp) {
      int pos = wv * 16 + pp;
      float2 c2 = cds[k * 64 + pos];
      float ys = c2.x, xs = c2.y;
      float y0f = floorf(ys), x0f = floorf(xs);
      float wy = ys - y0f, wx = xs - x0f;
      int iy0 = (int)y0f, ix0 = (int)x0f;
      int iy1 = iy0 + 1, ix1 = ix0 + 1;
      bool y0v = (iy0 >= 0) & (iy0 < H);
      bool y1v = (iy1 >= 0) & (iy1 < H);
      bool x0v = (ix0 >= 0) & (ix0 < W);
      bool x1v = (ix1 >= 0) & (ix1 < W);
      int yc0 = min(max(iy0, 0), H - 1), yc1 = min(max(iy1, 0), H - 1);
      int xc0 = min(max(ix0, 0), W - 1), xc1 = min(max(ix1, 0), W - 1);
      float w00 = (1.f - wy) * (1.f - wx) * (float)(y0v & x0v);
      float w01 = (1.f - wy) * wx * (float)(y0v & x1v);
      float w10 = wy * (1.f - wx) * (float)(y1v & x0v);
      float w11 = wy * wx * (float)(y1v & x1v);
      float a00 = bf2f(xtn[((size_t)(yc0 * W + xc0)) * C + ln]);
      float a01 = bf2f(xtn[((size_t)(yc0 * W + xc1)) * C + ln]);
      float a10 = bf2f(xtn[((size_t)(yc1 * W + xc0)) * C + ln]);
      float a11 = bf2f(xtn[((size_t)(yc1 * W + xc1)) * C + ln]);
      float v = w00 * a00 + w01 * a01 + w10 * a10 + w11 * a11;
      val_lds[pos * 64 + (ln ^ ((pos & 7) << 3))] = f2bf(v);
    }
    __syncthreads();
    // MFMA: wave wv computes co strip [wco, wco+16) x all 64 pos
#pragma unroll
    for (int ks = 0; ks < 2; ++ks) {
      int c0 = ks * 32 + lg * 8;
      int arow = wco + lr;
      short8 a = *(const short8*)&w_lds[arow * 64 + (c0 ^ ((arow & 7) << 3))];
#pragma unroll
      for (int tt = 0; tt < 4; ++tt) {
        int pos = tt * 16 + lr;
        short8 bf = *(const short8*)&val_lds[pos * 64 + (c0 ^ ((pos & 7) << 3))];
        acc[tt] = __builtin_amdgcn_mfma_f32_16x16x32_bf16(a, bf, acc[tt], 0, 0, 0);
      }
    }
  }

  // epilogue: bias, store preBN to d_out, BN partial sums
  float b4[4];
#pragma unroll
  for (int r = 0; r < 4; ++r) b4[r] = bias[wco + lg * 4 + r];
  float s1[4], s2[4];
#pragma unroll
  for (int r = 0; r < 4; ++r) { s1[r] = 0.f; s2[r] = 0.f; }
#pragma unroll
  for (int tt = 0; tt < 4; ++tt) {
    int pos = tt * 16 + lr;
    int h = ty0 + (pos >> 3), wc = tx0 + (pos & 7);
#pragma unroll
    for (int r = 0; r < 4; ++r) {
      float v = acc[tt][r] + b4[r];
      out[(((size_t)n * 64 + wco + lg * 4 + r) * H + h) * W + wc] = v;
      s1[r] += v;
      s2[r] += v * v;
    }
  }
#pragma unroll
  for (int r = 0; r < 4; ++r) {
#pragma unroll
    for (int m = 1; m < 16; m <<= 1) {
      s1[r] += __shfl_xor(s1[r], m, 64);
      s2[r] += __shfl_xor(s2[r], m, 64);
    }
  }
  if (lr == 0) {
#pragma unroll
    for (int r = 0; r < 4; ++r) {
      atomicAdd(&sums[wco + lg * 4 + r], s1[r]);
      atomicAdd(&sums[64 + wco + lg * 4 + r], s2[r]);
    }
  }
}

// ---------------- BN apply (in place on d_out)
__global__ __launch_bounds__(256) void bn_kernel(float* __restrict__ out,
                                                 const float* __restrict__ sums,
                                                 const float* __restrict__ gamma,
                                                 const float* __restrict__ beta) {
  size_t i4 = (size_t)blockIdx.x * 256 + threadIdx.x;
  size_t e = i4 * 4;
  int co = (int)((e >> 14) & 63);
  float s1 = sums[co], s2 = sums[64 + co];
  const float inv_n = 1.f / 131072.f;
  float mean = s1 * inv_n;
  float var = s2 * inv_n - mean * mean;
  float iv = rsqrtf(var + 1e-5f);
  float sc = gamma[co] * iv;
  float sh = beta[co] - mean * sc;
  float4 v = ((float4*)out)[i4];
  v.x = v.x * sc + sh;
  v.y = v.y * sc + sh;
  v.z = v.z * sc + sh;
  v.w = v.w * sc + sh;
  ((float4*)out)[i4] = v;
}

extern "C" void kernel_launch(void* const* d_in, const int* in_sizes, int n_in,
                              void* d_out, int out_size, void* d_ws, size_t ws_size,
                              hipStream_t stream) {
  (void)in_sizes; (void)n_in; (void)out_size; (void)ws_size;
  const float* x     = (const float*)d_in[0];
  const float* w_off = (const float*)d_in[1];
  const float* b_off = (const float*)d_in[2];
  const float* w     = (const float*)d_in[3];
  const float* bias  = (const float*)d_in[4];
  const float* gamma = (const float*)d_in[5];
  const float* beta  = (const float*)d_in[6];
  uint8_t* wsb = (uint8_t*)d_ws;
  ushort* xtp  = (ushort*)(wsb + XT_B);
  float2* cdp  = (float2*)(wsb + CD_B);
  ushort* wtp  = (ushort*)(wsb + WT_B);
  float* sums  = (float*)(wsb + SUM_B);
  float* out   = (float*)d_out;

  hipLaunchKernelGGL(prep_kernel, dim3(1041), dim3(256), 0, stream, x, w, xtp, wtp, sums);
  hipLaunchKernelGGL(offs_kernel, dim3(512), dim3(256), 0, stream, x, w_off, b_off, cdp);
  hipLaunchKernelGGL(conv_kernel, dim3(2048), dim3(256), 0, stream, xtp, cdp, wtp, bias, out, sums);
  hipLaunchKernelGGL(bn_kernel, dim3(8192), dim3(256), 0, stream, out, sums, gamma, beta);
}

// Round 4
// 283.808 us; speedup vs baseline: 1.6570x; 1.6570x over previous
//
#include <hip/hip_runtime.h>
#include <hip/hip_bf16.h>

#define H 128
#define W 128
#define C 64
#define NB 8

typedef __attribute__((ext_vector_type(4))) float f32x4;
typedef __attribute__((ext_vector_type(8))) short short8;

// ws layout (bytes)
static constexpr size_t XT_B  = 0;         // bf16 xt [N][H][W][C]   16777216 B
static constexpr size_t CD_B  = 16777216;  // float2 cd [N][9][H][W]  9437184 B
static constexpr size_t WT_B  = 26214400;  // bf16 wt [9][co][c]        73728 B
static constexpr size_t WO_B  = 26288128;  // bf16 wo [9][32(o)][c]     36864 B
static constexpr size_t SUM_B = 26324992;  // f32 sums [4][128]          2048 B

__device__ __forceinline__ ushort f2bf(float f) {
  uint u = __float_as_uint(f);
  return (ushort)((u + 0x7fffu + ((u >> 16) & 1u)) >> 16);
}

union PackBF { __hip_bfloat162 h[4]; short8 s; };
union QS8 { uint4 q; short8 s; };

#define UNPACK_FMA(q, wgt, m)                                  \
  m[0] += (wgt) * __uint_as_float((q).x << 16);                \
  m[1] += (wgt) * __uint_as_float((q).x & 0xffff0000u);        \
  m[2] += (wgt) * __uint_as_float((q).y << 16);                \
  m[3] += (wgt) * __uint_as_float((q).y & 0xffff0000u);        \
  m[4] += (wgt) * __uint_as_float((q).z << 16);                \
  m[5] += (wgt) * __uint_as_float((q).z & 0xffff0000u);        \
  m[6] += (wgt) * __uint_as_float((q).w << 16);                \
  m[7] += (wgt) * __uint_as_float((q).w & 0xffff0000u);

// ---------------- prep: x NCHW->NHWC bf16; w -> wt[k][co][c]; w_off -> wo[k][o][c]; zero sums
__global__ __launch_bounds__(256) void prep_kernel(const float* __restrict__ x,
                                                   const float* __restrict__ w,
                                                   const float* __restrict__ w_off,
                                                   ushort* __restrict__ xt,
                                                   ushort* __restrict__ wt,
                                                   ushort* __restrict__ wo,
                                                   float* __restrict__ sums) {
  int b = blockIdx.x, t = threadIdx.x;
  if (b < 1024) {
    __shared__ float lds[64 * 129];
    int n = b >> 7, h = b & 127;
    const float* xp = x + ((size_t)n * C) * H * W + (size_t)h * W;
    for (int i = t; i < 8192; i += 256) {
      int c = i >> 7, ww = i & 127;
      lds[c * 129 + ww] = xp[(size_t)c * H * W + ww];
    }
    __syncthreads();
    ushort* xo = xt + (((size_t)n * H + h) * W) * C;
    for (int i = t; i < 8192; i += 256) {
      int ww = i >> 6, c = i & 63;
      xo[(size_t)ww * C + c] = f2bf(lds[c * 129 + ww]);
    }
  } else if (b < 1040) {
    int base = (b - 1024) * 2304;
    for (int i = t; i < 2304; i += 256) {
      int idx = base + i;               // idx = co*576 + c*9 + kk
      int co = idx / 576;
      int rem = idx % 576;
      int c = rem / 9, kk = rem % 9;
      wt[(size_t)kk * 4096 + co * 64 + c] = f2bf(w[idx]);
    }
  } else if (b < 1048) {
    int base = (b - 1040) * 2304;
    for (int i = t; i < 2304; i += 256) {
      int idx = base + i;               // idx = k*2048 + o*64 + c
      int k = idx >> 11, o = (idx >> 6) & 31, c = idx & 63;
      wo[idx] = (o < 18) ? f2bf(w_off[((size_t)(o * 64 + c)) * 9 + k]) : (ushort)0;
    }
  } else {
    // zero ALL 512 sum slots (4 atomic-reduction copies x 128)
    sums[t] = 0.0f;
    sums[t + 256] = 0.0f;
  }
}

// ---------------- offset conv via bf16 MFMA reading xt; writes sample coords
__global__ __launch_bounds__(256) void offs_kernel(const ushort* __restrict__ xt,
                                                   const ushort* __restrict__ wo,
                                                   const float* __restrict__ b_off,
                                                   float2* __restrict__ cd) {
  int b = blockIdx.x;
  int n = b >> 8;
  int tile = b & 255;
  int ty0 = (tile >> 4) << 3;
  int tx0 = (tile & 15) << 3;
  int t = threadIdx.x;
  int wv = t >> 6, ln = t & 63;
  int lr = ln & 15, lg = ln >> 4;
  int mypos = wv * 16 + lr;
  int ph = ty0 + (mypos >> 3), pw = tx0 + (mypos & 7);
  int cb = lg << 3;
  const ushort* xtn = xt + ((size_t)n << 20);

  f32x4 acc0 = {0.f, 0.f, 0.f, 0.f}, acc1 = {0.f, 0.f, 0.f, 0.f};
#pragma unroll
  for (int k = 0; k < 9; ++k) {
    int ky = k / 3 - 1, kx = k % 3 - 1;
    int gy = ph + ky, gx = pw + kx;
    bool v = (gy >= 0) & (gy < H) & (gx >= 0) & (gx < W);
    int gyc = min(max(gy, 0), H - 1), gxc = min(max(gx, 0), W - 1);
    uint p = (uint)((gyc << 7) + gxc) << 6;
    QS8 qa, qb;
    qa.q = *(const uint4*)(xtn + p + cb);
    qb.q = *(const uint4*)(xtn + p + cb + 32);
    uint msk = v ? 0xffffffffu : 0u;
    qa.q.x &= msk; qa.q.y &= msk; qa.q.z &= msk; qa.q.w &= msk;
    qb.q.x &= msk; qb.q.y &= msk; qb.q.z &= msk; qb.q.w &= msk;
    const ushort* wk = wo + (k << 11);
    short8 b00 = *(const short8*)(wk + (lr << 6) + cb);
    short8 b01 = *(const short8*)(wk + (lr << 6) + 32 + cb);
    short8 b10 = *(const short8*)(wk + ((16 + lr) << 6) + cb);
    short8 b11 = *(const short8*)(wk + ((16 + lr) << 6) + 32 + cb);
    acc0 = __builtin_amdgcn_mfma_f32_16x16x32_bf16(qa.s, b00, acc0, 0, 0, 0);
    acc0 = __builtin_amdgcn_mfma_f32_16x16x32_bf16(qb.s, b01, acc0, 0, 0, 0);
    acc1 = __builtin_amdgcn_mfma_f32_16x16x32_bf16(qa.s, b10, acc1, 0, 0, 0);
    acc1 = __builtin_amdgcn_mfma_f32_16x16x32_bf16(qb.s, b11, acc1, 0, 0, 0);
  }
  // D[pos][o]: lane holds o = ot*16+lr (cols), pos = wv*16 + lg*4 + r (rows)
  float bo0 = b_off[lr];
  float bo1 = (lr < 2) ? b_off[16 + lr] : 0.f;
  int rh[4], rw[4];
#pragma unroll
  for (int r = 0; r < 4; ++r) {
    int pos = wv * 16 + lg * 4 + r;
    rh[r] = ty0 + (pos >> 3);
    rw[r] = tx0 + (pos & 7);
  }
  float v0[4], p0[4], v1[4], p1[4];
#pragma unroll
  for (int r = 0; r < 4; ++r) { v0[r] = acc0[r] + bo0; v1[r] = acc1[r] + bo1; }
#pragma unroll
  for (int r = 0; r < 4; ++r) { p0[r] = __shfl_xor(v0[r], 1); p1[r] = __shfl_xor(v1[r], 1); }
  if (!(lr & 1)) {
    int k = lr >> 1;  // 0..7
    int ky = k / 3 - 1, kx = k % 3 - 1;
    float2* cdn = cd + (((size_t)n * 9 + k) << 14);
#pragma unroll
    for (int r = 0; r < 4; ++r)
      cdn[(rh[r] << 7) + rw[r]] = make_float2((float)(rh[r] + ky) + v0[r],
                                              (float)(rw[r] + kx) + p0[r]);
    if (lr == 0) {
      float2* cd8 = cd + (((size_t)n * 9 + 8) << 14);
#pragma unroll
      for (int r = 0; r < 4; ++r)
        cd8[(rh[r] << 7) + rw[r]] = make_float2((float)(rh[r] + 1) + v1[r],
                                                (float)(rw[r] + 1) + p1[r]);
    }
  }
}

// ---------------- deformable conv: reg-gather -> bf16 MFMA, no main-loop barriers
__global__ __launch_bounds__(256) void conv_kernel(const ushort* __restrict__ xt,
                                                   const float2* __restrict__ cd,
                                                   const ushort* __restrict__ wt,
                                                   const float* __restrict__ bias,
                                                   float* __restrict__ out,
                                                   float* __restrict__ sums) {
  int b = blockIdx.x;
  int n = b >> 8;
  int tile = b & 255;
  int ty0 = (tile >> 4) << 3;
  int tx0 = (tile & 15) << 3;
  int t = threadIdx.x;
  int wv = t >> 6, ln = t & 63;
  int lr = ln & 15, lg = ln >> 4;
  int mypos = wv * 16 + lr;
  int ph = ty0 + (mypos >> 3), pw = tx0 + (mypos & 7);
  int cb = lg << 3;

  __shared__ float red[4][64][2];

  const ushort* xtn = xt + ((size_t)n << 20);
  const float2* cdn = cd + (((size_t)n * 9) << 14) + (ph << 7) + pw;

  f32x4 acc[4];
#pragma unroll
  for (int ct = 0; ct < 4; ++ct) acc[ct] = (f32x4)(0.f);

#pragma unroll
  for (int k = 0; k < 9; ++k) {
    float2 c2 = cdn[(size_t)k << 14];
    float ys = c2.x, xs = c2.y;
    float y0f = floorf(ys), x0f = floorf(xs);
    float wy = ys - y0f, wx = xs - x0f;
    int iy0 = (int)y0f, ix0 = (int)x0f;
    int iy1 = iy0 + 1, ix1 = ix0 + 1;
    bool y0v = (iy0 >= 0) & (iy0 < H);
    bool y1v = (iy1 >= 0) & (iy1 < H);
    bool x0v = (ix0 >= 0) & (ix0 < W);
    bool x1v = (ix1 >= 0) & (ix1 < W);
    int yc0 = min(max(iy0, 0), H - 1), yc1 = min(max(iy1, 0), H - 1);
    int xc0 = min(max(ix0, 0), W - 1), xc1 = min(max(ix1, 0), W - 1);
    float w00 = (1.f - wy) * (1.f - wx) * (float)(y0v & x0v);
    float w01 = (1.f - wy) * wx * (float)(y0v & x1v);
    float w10 = wy * (1.f - wx) * (float)(y1v & x0v);
    float w11 = wy * wx * (float)(y1v & x1v);
    uint p00 = (uint)((yc0 << 7) + xc0) << 6;
    uint p01 = (uint)((yc0 << 7) + xc1) << 6;
    uint p10 = (uint)((yc1 << 7) + xc0) << 6;
    uint p11 = (uint)((yc1 << 7) + xc1) << 6;
    uint4 q00a = *(const uint4*)(xtn + p00 + cb);
    uint4 q00b = *(const uint4*)(xtn + p00 + cb + 32);
    uint4 q01a = *(const uint4*)(xtn + p01 + cb);
    uint4 q01b = *(const uint4*)(xtn + p01 + cb + 32);
    uint4 q10a = *(const uint4*)(xtn + p10 + cb);
    uint4 q10b = *(const uint4*)(xtn + p10 + cb + 32);
    uint4 q11a = *(const uint4*)(xtn + p11 + cb);
    uint4 q11b = *(const uint4*)(xtn + p11 + cb + 32);
    float m0[8] = {0.f, 0.f, 0.f, 0.f, 0.f, 0.f, 0.f, 0.f};
    float m1[8] = {0.f, 0.f, 0.f, 0.f, 0.f, 0.f, 0.f, 0.f};
    UNPACK_FMA(q00a, w00, m0); UNPACK_FMA(q00b, w00, m1);
    UNPACK_FMA(q01a, w01, m0); UNPACK_FMA(q01b, w01, m1);
    UNPACK_FMA(q10a, w10, m0); UNPACK_FMA(q10b, w10, m1);
    UNPACK_FMA(q11a, w11, m0); UNPACK_FMA(q11b, w11, m1);
    PackBF a0, a1;
#pragma unroll
    for (int j = 0; j < 4; ++j) {
      a0.h[j] = __float22bfloat162_rn(make_float2(m0[2 * j], m0[2 * j + 1]));
      a1.h[j] = __float22bfloat162_rn(make_float2(m1[2 * j], m1[2 * j + 1]));
    }
    const ushort* wk = wt + (k << 12);
#pragma unroll
    for (int ct = 0; ct < 4; ++ct) {
      short8 b0 = *(const short8*)(wk + ((ct * 16 + lr) << 6) + cb);
      short8 b1 = *(const short8*)(wk + ((ct * 16 + lr) << 6) + 32 + cb);
      acc[ct] = __builtin_amdgcn_mfma_f32_16x16x32_bf16(a0.s, b0, acc[ct], 0, 0, 0);
      acc[ct] = __builtin_amdgcn_mfma_f32_16x16x32_bf16(a1.s, b1, acc[ct], 0, 0, 0);
    }
  }

  // epilogue: D[pos][co]; lane: co = ct*16+lr, pos = wv*16 + lg*4 + r
  float bi[4];
#pragma unroll
  for (int ct = 0; ct < 4; ++ct) bi[ct] = bias[ct * 16 + lr];
  int phw[4];
#pragma unroll
  for (int r = 0; r < 4; ++r) {
    int pos = wv * 16 + lg * 4 + r;
    phw[r] = ((ty0 + (pos >> 3)) << 7) + tx0 + (pos & 7);
  }
  float s1[4], s2[4];
#pragma unroll
  for (int ct = 0; ct < 4; ++ct) { s1[ct] = 0.f; s2[ct] = 0.f; }
#pragma unroll
  for (int ct = 0; ct < 4; ++ct) {
    size_t cbase = ((size_t)(n * 64 + ct * 16 + lr)) << 14;
#pragma unroll
    for (int r = 0; r < 4; ++r) {
      float v = acc[ct][r] + bi[ct];
      out[cbase + phw[r]] = v;
      s1[ct] += v;
      s2[ct] += v * v;
    }
  }
#pragma unroll
  for (int ct = 0; ct < 4; ++ct) {
    s1[ct] += __shfl_xor(s1[ct], 16);
    s1[ct] += __shfl_xor(s1[ct], 32);
    s2[ct] += __shfl_xor(s2[ct], 16);
    s2[ct] += __shfl_xor(s2[ct], 32);
  }
  if (lg == 0) {
#pragma unroll
    for (int ct = 0; ct < 4; ++ct) {
      red[wv][ct * 16 + lr][0] = s1[ct];
      red[wv][ct * 16 + lr][1] = s2[ct];
    }
  }
  __syncthreads();
  if (t < 128) {
    int co = t & 63, j = t >> 6;
    float s = red[0][co][j] + red[1][co][j] + red[2][co][j] + red[3][co][j];
    atomicAdd(&sums[(b & 3) * 128 + j * 64 + co], s);
  }
}

// ---------------- BN apply (in place on d_out)
__global__ __launch_bounds__(256) void bn_kernel(float* __restrict__ out,
                                                 const float* __restrict__ sums,
                                                 const float* __restrict__ gamma,
                                                 const float* __restrict__ beta) {
  size_t i4 = (size_t)blockIdx.x * 256 + threadIdx.x;
  size_t e = i4 * 4;
  int co = (int)((e >> 14) & 63);
  float s1 = sums[co] + sums[128 + co] + sums[256 + co] + sums[384 + co];
  float s2 = sums[64 + co] + sums[192 + co] + sums[320 + co] + sums[448 + co];
  const float inv_n = 1.f / 131072.f;
  float mean = s1 * inv_n;
  float var = s2 * inv_n - mean * mean;
  float iv = rsqrtf(var + 1e-5f);
  float sc = gamma[co] * iv;
  float sh = beta[co] - mean * sc;
  float4 v = ((float4*)out)[i4];
  v.x = v.x * sc + sh;
  v.y = v.y * sc + sh;
  v.z = v.z * sc + sh;
  v.w = v.w * sc + sh;
  ((float4*)out)[i4] = v;
}

extern "C" void kernel_launch(void* const* d_in, const int* in_sizes, int n_in,
                              void* d_out, int out_size, void* d_ws, size_t ws_size,
                              hipStream_t stream) {
  (void)in_sizes; (void)n_in; (void)out_size; (void)ws_size;
  const float* x     = (const float*)d_in[0];
  const float* w_off = (const float*)d_in[1];
  const float* b_off = (const float*)d_in[2];
  const float* w     = (const float*)d_in[3];
  const float* bias  = (const float*)d_in[4];
  const float* gamma = (const float*)d_in[5];
  const float* beta  = (const float*)d_in[6];
  uint8_t* wsb = (uint8_t*)d_ws;
  ushort* xtp  = (ushort*)(wsb + XT_B);
  float2* cdp  = (float2*)(wsb + CD_B);
  ushort* wtp  = (ushort*)(wsb + WT_B);
  ushort* wop  = (ushort*)(wsb + WO_B);
  float* sums  = (float*)(wsb + SUM_B);
  float* out   = (float*)d_out;

  hipLaunchKernelGGL(prep_kernel, dim3(1049), dim3(256), 0, stream, x, w, w_off, xtp, wtp, wop, sums);
  hipLaunchKernelGGL(offs_kernel, dim3(2048), dim3(256), 0, stream, xtp, wop, b_off, cdp);
  hipLaunchKernelGGL(conv_kernel, dim3(2048), dim3(256), 0, stream, xtp, cdp, wtp, bias, out, sums);
  hipLaunchKernelGGL(bn_kernel, dim3(8192), dim3(256), 0, stream, out, sums, gamma, beta);
}